// Round 1
// baseline (71.956 us; speedup 1.0000x reference)
//
#include <hip/hip_runtime.h>
#include <hip/hip_bf16.h>

#define HW 9216   // 96*96
#define CIN 128
#define COUT 128

// ---------------- Kernel 1: q = w_q @ x, k = w_k @ x ----------------
// grid (144, 2), block 256. Strip of 64 pixels, all 256 outputs (128 q + 128 k).
// Thread register tile: 8 outs x 8 pixels.
__global__ __launch_bounds__(256) void conv1x1_qk(
    const float* __restrict__ x,   // [2][128][9216]
    const float* __restrict__ wq,  // [128][128] (o, i)
    const float* __restrict__ wk,
    float* __restrict__ qbuf,      // [2][128][9216]
    float* __restrict__ kbuf)
{
    __shared__ __align__(16) float xs[CIN * 64];   // [i][p], stride 64
    __shared__ __align__(16) float ws[16 * 260];   // [klocal][o], stride 260 (16B-aligned rows)

    const int tid = threadIdx.x;
    const int b = blockIdx.y;
    const int pixbase = blockIdx.x * 64;

    // load x strip: 128 ch x 64 pix
    const float* xb = x + (size_t)b * CIN * HW + pixbase;
    #pragma unroll
    for (int i = 0; i < 32; ++i) {
        int flat = tid + i * 256;
        int p = flat & 63, ch = flat >> 6;
        xs[ch * 64 + p] = xb[ch * HW + p];
    }

    const int pg = tid & 7;    // pixels p = pg*8 .. +7
    const int og = tid >> 3;   // outs   o = og*8 .. +7

    float acc[8][8];
    #pragma unroll
    for (int j = 0; j < 8; ++j)
        #pragma unroll
        for (int i = 0; i < 8; ++i) acc[j][i] = 0.f;

    for (int kb = 0; kb < 128; kb += 16) {
        __syncthreads();   // previous ws reads done
        // load w chunk [16 k][256 o]
        #pragma unroll
        for (int i = 0; i < 16; ++i) {
            int flat = tid + i * 256;          // 0..4095
            int kl = flat & 15, o = flat >> 4; // o: 0..255
            const float* src = (o < 128) ? (wq + o * 128) : (wk + (o - 128) * 128);
            ws[kl * 260 + o] = src[kb + kl];
        }
        __syncthreads();
        #pragma unroll
        for (int kk = 0; kk < 16; ++kk) {
            float4 w0 = *(const float4*)&ws[kk * 260 + og * 8];
            float4 w1 = *(const float4*)&ws[kk * 260 + og * 8 + 4];
            float4 x0 = *(const float4*)&xs[(kb + kk) * 64 + pg * 8];
            float4 x1 = *(const float4*)&xs[(kb + kk) * 64 + pg * 8 + 4];
            float wv[8] = {w0.x, w0.y, w0.z, w0.w, w1.x, w1.y, w1.z, w1.w};
            float xv[8] = {x0.x, x0.y, x0.z, x0.w, x1.x, x1.y, x1.z, x1.w};
            #pragma unroll
            for (int j = 0; j < 8; ++j)
                #pragma unroll
                for (int i = 0; i < 8; ++i)
                    acc[j][i] = fmaf(wv[j], xv[i], acc[j][i]);
        }
    }

    #pragma unroll
    for (int j = 0; j < 8; ++j) {
        int o = og * 8 + j;
        float* dst = (o < 128) ? (qbuf + ((size_t)b * COUT + o) * HW)
                               : (kbuf + ((size_t)b * COUT + (o - 128)) * HW);
        float4 s0 = {acc[j][0], acc[j][1], acc[j][2], acc[j][3]};
        float4 s1 = {acc[j][4], acc[j][5], acc[j][6], acc[j][7]};
        *(float4*)&dst[pixbase + pg * 8]     = s0;
        *(float4*)&dst[pixbase + pg * 8 + 4] = s1;
    }
}

// ---------------- Kernel 2: windowed softmax attention ----------------
// grid (9, 256): 3x3 tiles of 32x32 per (b,c) plane. block 256 = 8 col-groups x 32 rows.
// Each thread: 4 consecutive outputs along w. No max-subtraction (logits bounded << 88).
__global__ __launch_bounds__(256) void attn_win(
    const float* __restrict__ qbuf,
    const float* __restrict__ kbuf,
    const float* __restrict__ v,
    const float* __restrict__ rel_h,  // [64][7]
    const float* __restrict__ rel_w,  // [64][7]
    float* __restrict__ out)
{
    __shared__ __align__(16) float ks[38 * 40];
    __shared__ __align__(16) float vs[38 * 40];

    const int tid = threadIdx.x;
    const int tile = blockIdx.x;           // 0..8
    const int bc = blockIdx.y;             // 0..255
    const int c = bc & 127;
    const int tw = (tile % 3) * 32;
    const int th = (tile / 3) * 32;

    const float* kp = kbuf + (size_t)bc * HW;
    const float* vp = v    + (size_t)bc * HW;

    // halo load: rows th-3..th+34, cols tw-3..tw+34 (38x38), zero-padded
    for (int it = 0; it < 6; ++it) {
        int idx = tid + it * 256;
        if (idx < 38 * 38) {
            int r = idx / 38, cl = idx - r * 38;
            int gr = th - 3 + r, gc = tw - 3 + cl;
            bool ok = ((unsigned)gr < 96u) && ((unsigned)gc < 96u);
            float kv = ok ? kp[gr * 96 + gc] : 0.f;
            float vv = ok ? vp[gr * 96 + gc] : 0.f;
            ks[r * 40 + cl] = kv;
            vs[r * 40 + cl] = vv;
        }
    }

    const bool is_h = (c < 64);
    const float* rbase = is_h ? (rel_h + c * 7) : (rel_w + (c - 64) * 7);
    float r7[7];
    #pragma unroll
    for (int i = 0; i < 7; ++i) r7[i] = rbase[i];

    const int tx = tid & 7;    // col group: w = tw + tx*4 .. +3
    const int ty = tid >> 3;   // row:       h = th + ty

    const float* qrow = qbuf + (size_t)bc * HW + (th + ty) * 96 + tw + tx * 4;
    float4 qv = *(const float4*)qrow;
    float q2[4] = {qv.x * 1.4426950408889634f, qv.y * 1.4426950408889634f,
                   qv.z * 1.4426950408889634f, qv.w * 1.4426950408889634f};

    float s[4] = {0.f, 0.f, 0.f, 0.f};
    float a[4] = {0.f, 0.f, 0.f, 0.f};

    __syncthreads();

    #pragma unroll
    for (int dh = 0; dh < 7; ++dh) {
        const float* kr0 = &ks[(ty + dh) * 40 + tx * 4];
        const float* vr0 = &vs[(ty + dh) * 40 + tx * 4];
        float kr[12], vr[12];
        *(float4*)&kr[0] = *(const float4*)&kr0[0];
        *(float4*)&kr[4] = *(const float4*)&kr0[4];
        *(float4*)&kr[8] = *(const float4*)&kr0[8];
        *(float4*)&vr[0] = *(const float4*)&vr0[0];
        *(float4*)&vr[4] = *(const float4*)&vr0[4];
        *(float4*)&vr[8] = *(const float4*)&vr0[8];

        float ad[7];
        float ah = r7[dh];
        #pragma unroll
        for (int dw = 0; dw < 7; ++dw) ad[dw] = is_h ? ah : r7[dw];

        #pragma unroll
        for (int j = 0; j < 4; ++j) {
            #pragma unroll
            for (int dw = 0; dw < 7; ++dw) {
                float t = kr[j + dw] + ad[dw];
                float e = exp2f(q2[j] * t);
                s[j] += e;
                a[j] = fmaf(e, vr[j + dw], a[j]);
            }
        }
    }

    float4 o4 = {a[0] / s[0], a[1] / s[1], a[2] / s[2], a[3] / s[3]};
    float* orow = out + (size_t)bc * HW + (th + ty) * 96 + tw + tx * 4;
    *(float4*)orow = o4;
}

extern "C" void kernel_launch(void* const* d_in, const int* in_sizes, int n_in,
                              void* d_out, int out_size, void* d_ws, size_t ws_size,
                              hipStream_t stream) {
    const float* x  = (const float*)d_in[0];
    const float* v  = (const float*)d_in[1];
    const float* wq = (const float*)d_in[2];
    const float* wk = (const float*)d_in[3];
    const float* rh = (const float*)d_in[4];
    const float* rw = (const float*)d_in[5];
    float* out = (float*)d_out;

    float* qbuf = (float*)d_ws;                       // 2*128*9216 f32
    float* kbuf = qbuf + (size_t)2 * COUT * HW;       // 2*128*9216 f32

    conv1x1_qk<<<dim3(144, 2), 256, 0, stream>>>(x, wq, wk, qbuf, kbuf);
    attn_win<<<dim3(9, 256), 256, 0, stream>>>(qbuf, kbuf, v, rh, rw, out);
}